// Round 15
// baseline (5581.533 us; speedup 1.0000x reference)
//
#include <hip/hip_runtime.h>
#include <cstdint>

#define Bb 32
#define Cc 512
#define Nn 384
#define Vv 600
#define Ee 256
#define Dd 512
#define Tt 192
#define Ss 191
#define EOS_TOK 130
#define BD (Bb*Dd)          // 16384
#define NBLK 256
#define NTHR 512

// ---- ws layout (float offsets) ----
#define OFF_TOK   0                      // int tok[Ss*Bb]
#define OFF_SHIFT 8192                   // float shift[1]
#define OFF_WV    8256                   // Bb*Nn*Dd = 6291456
#define OFF_HXT   6299712                // 2*16384 hxT [par][d][b] (sc1)
#define OFF_XO    6332480                // 16384 xo [d][b] (sc1)
#define OFF_HXB   6348864                // 2*16384 hxB [par][b][d] (sc1) — parity vs straggler F
#define OFF_DEN   6381632                // den[t][b] 191*32 (pad 8192, zeroed once)
#define OFF_Q     6389824                // q[b][d] 32*512 (sc1)
#define OFF_CTXB  6406208                // ctxB[b][c] 32*512 (atomics + sc1)
#define OFF_OBUF  6422592                // 192*BD; slot t+1 front doubles as embx[t]
#define OFF_BAR   9568320                // flags+genv+qdone+dedone+fdone

#define LOGITS_SZ (Bb*Ss*Vv)  // 3667200
#define ALPHA_SZ  (Bb*Ss*Nn)  // 2347008

__device__ __forceinline__ float sigm_(float x) {
    float e = __expf(-x);
    return __builtin_amdgcn_rcpf(1.0f + e);
}
__device__ __forceinline__ float tanh_(float x) {
    float xc = fminf(15.0f, fmaxf(-15.0f, x));
    float e = __expf(2.0f * xc);
    return (e - 1.0f) * __builtin_amdgcn_rcpf(e + 1.0f);
}

// Write-through device store (sc1): at LLC once vmcnt retires; __syncthreads
// drains vmcnt, so no release fence is ever needed.
__device__ __forceinline__ void st_dev(float* p, float v) {
    __hip_atomic_store(p, v, __ATOMIC_RELAXED, __HIP_MEMORY_SCOPE_AGENT);
}
__device__ __forceinline__ float ld1_dev(const float* p) {
    return __hip_atomic_load(p, __ATOMIC_RELAXED, __HIP_MEMORY_SCOPE_AGENT);
}
// 8-byte coherent load (sc1 bypass, relaxed).
__device__ __forceinline__ float2 ld2_dev(const float* p) {
    unsigned long long u = __hip_atomic_load((const unsigned long long*)p,
                                             __ATOMIC_RELAXED,
                                             __HIP_MEMORY_SCOPE_AGENT);
    float2 f;
    f.x = __uint_as_float((unsigned int)u);
    f.y = __uint_as_float((unsigned int)(u >> 32));
    return f;
}

// Flag-array device barrier (proven aggregator protocol) — ONE per step now.
__device__ __forceinline__ void gbar(int* flags, int* genv, int ibar) {
    __syncthreads();   // drains vmcnt: all sc1 data stores ack'd at LLC
    const int target = ibar + 1;
    if (threadIdx.x == 0)
        __hip_atomic_store(&flags[blockIdx.x * 16], target, __ATOMIC_RELAXED,
                           __HIP_MEMORY_SCOPE_AGENT);
    if (blockIdx.x == 0) {
        if (threadIdx.x < 64) {
            int l = threadIdx.x * 4;
            for (;;) {
                int f0 = __hip_atomic_load(&flags[(l + 0) * 16], __ATOMIC_RELAXED,
                                           __HIP_MEMORY_SCOPE_AGENT);
                int f1 = __hip_atomic_load(&flags[(l + 1) * 16], __ATOMIC_RELAXED,
                                           __HIP_MEMORY_SCOPE_AGENT);
                int f2 = __hip_atomic_load(&flags[(l + 2) * 16], __ATOMIC_RELAXED,
                                           __HIP_MEMORY_SCOPE_AGENT);
                int f3 = __hip_atomic_load(&flags[(l + 3) * 16], __ATOMIC_RELAXED,
                                           __HIP_MEMORY_SCOPE_AGENT);
                if (__all(f0 >= target && f1 >= target &&
                          f2 >= target && f3 >= target)) break;
                __builtin_amdgcn_s_sleep(1);
            }
            if (threadIdx.x < 32)
                __hip_atomic_store(&genv[threadIdx.x * 16], target,
                                   __ATOMIC_RELAXED, __HIP_MEMORY_SCOPE_AGENT);
        }
    } else if (threadIdx.x == 0) {
        int* g = &genv[(blockIdx.x >> 3) * 16];
        while (__hip_atomic_load(g, __ATOMIC_RELAXED,
                                 __HIP_MEMORY_SCOPE_AGENT) < target)
            __builtin_amdgcn_s_sleep(2);
    }
    __syncthreads();
}

// Block-wide 8-flag group poll (q/ctx handoff; proven in r9).
__device__ __forceinline__ void poll8(int* base, int grp, int target) {
    if (threadIdx.x < 64) {
        int* g = &base[(grp * 8 + (threadIdx.x & 7)) * 16];
        while (__hip_atomic_load(g, __ATOMIC_RELAXED,
                                 __HIP_MEMORY_SCOPE_AGENT) < target)
            __builtin_amdgcn_s_sleep(1);
    }
    __syncthreads();
}

// S0: zero state/flags/denoms, token sequence, exp-shift = sum|v|.
__global__ void k_setup(const int* __restrict__ tgt, const float* __restrict__ vv,
                        float* zbase, int* bar, int* tok, float* shiftbuf) {
    int gid = blockIdx.x * 256 + threadIdx.x;
    for (int i = gid; i < 90112; i += 96 * 256) zbase[i] = 0.f;   // hxT,xo,hxB,den
    if (gid < 16896) bar[gid] = 0;  // flags+genv+qdone+dedone+fdone
    if (blockIdx.x == 0) {
        __shared__ int is64;
        if (threadIdx.x == 0) {
            int a = 1;
            for (int k = 0; k < 32; ++k) if (tgt[2 * k + 1] != 0) a = 0;
            is64 = a;
        }
        __syncthreads();
        int b = threadIdx.x;
        if (b < Bb) {
            int fin = 0;
            tok[0 * Bb + b] = 0;
            for (int s = 1; s < Ss; ++s) {
                int li = b * Tt + s;
                int nt = is64 ? tgt[2 * li] : tgt[li];
                if (nt == EOS_TOK) fin = 1;
                tok[s * Bb + b] = fin ? 0 : nt;
            }
        }
    }
    if (blockIdx.x == 1) {
        __shared__ float sred[256];
        int tid = threadIdx.x;
        sred[tid] = fabsf(vv[tid]) + fabsf(vv[tid + 256]);
        __syncthreads();
        for (int s = 128; s > 0; s >>= 1) {
            if (tid < s) sred[tid] += sred[tid + s];
            __syncthreads();
        }
        if (tid == 0) shiftbuf[0] = sred[0];
    }
}

// S1: gather embeddings for all steps into obuf slot fronts: [t][k][b]
__global__ void k_embx(const float* __restrict__ emb, const int* __restrict__ tok,
                       float* __restrict__ obuf) {
    int i = blockIdx.x * 256 + threadIdx.x;
    if (i < Ss * 8192) {
        int t = i >> 13, e = i & 8191;
        int k = e >> 5, b = e & 31;
        obuf[(size_t)(t + 1) * BD + e] = emb[(size_t)tok[t * 32 + b] * Ee + k];
    }
}

// S2: Wv[b,n,d] = sum_c enc[b,n,c] * W_v[c,d]
__global__ void k_wv(const float* __restrict__ enc, const float* __restrict__ Wv_w,
                     float* __restrict__ Wv) {
    int b = blockIdx.x / 24, nt = blockIdx.x % 24, n0 = nt * 16;
    __shared__ float encL[16 * 512];
    for (int i = 0; i < 32; ++i) {
        int e = threadIdx.x + i * 256;
        int ni = e >> 9, c = e & 511;
        encL[e] = enc[((b * Nn) + (n0 + ni)) * Cc + c];
    }
    __syncthreads();
    int d0 = threadIdx.x, d1 = threadIdx.x + 256;
    float a0[16], a1[16];
#pragma unroll
    for (int i = 0; i < 16; ++i) { a0[i] = 0.f; a1[i] = 0.f; }
    for (int c = 0; c < 512; ++c) {
        float w0 = Wv_w[c * Dd + d0], w1 = Wv_w[c * Dd + d1];
#pragma unroll
        for (int i = 0; i < 16; ++i) {
            float ev = encL[i * 512 + c];
            a0[i] += ev * w0; a1[i] += ev * w1;
        }
    }
#pragma unroll
    for (int i = 0; i < 16; ++i) {
        Wv[((b * Nn) + (n0 + i)) * Dd + d0] = a0[i];
        Wv[((b * Nn) + (n0 + i)) * Dd + d1] = a1[i];
    }
}

// Persistent decode: 256 blocks x 512 threads; ONE global barrier per step.
// Per step: A { prework (emb+hx GEMV rows; deps crossed gbar(t-1)) ->
// poll 40 fdone flags (the 32 F-jobs producing this block's o-dims + the 8
// F-jobs reading its ctxB slice) -> ctx-zero + o-rows -> LSTM } -> gbar ->
// C -> qdone -> DE -> dedone -> F -> post fdone.
// Race closure: hxB parity-buffered (A(t) writes [t&1]; straggler F(t-1)
// reads [(t-1)&1]); xo written by F(t) only after gbar(t) which follows all
// A(t) xo-reads; hxT[par] written by A(t) only after the fdone poll, which
// implies all blocks passed gbar(t-1), i.e. all A(t-1) reads of that parity
// are complete; emb front of slot t+1 is consumed by A(t) before F(t)
// overwrites the slot (F runs post-gbar(t)).
__global__ __launch_bounds__(NTHR) void k_decode(
    const float* __restrict__ enc, const float* __restrict__ W_ih,
    const float* __restrict__ b_ih, const float* __restrict__ W_hh,
    const float* __restrict__ b_hh, const float* __restrict__ W_h,
    const float* __restrict__ vv, const float* __restrict__ W_c,
    const float* __restrict__ b_c, const float* __restrict__ Wv,
    const float* __restrict__ shiftbuf,
    float* __restrict__ hxT, float* __restrict__ xo, float* __restrict__ hxB,
    float* __restrict__ den, float* __restrict__ q, float* __restrict__ ctxB,
    float* __restrict__ obuf, float* __restrict__ alpha_e, int* bar)
{
    __shared__ float Wg[1280 * 8];    // A: gate cols [k][g*2+dd]  40960B
    __shared__ float scratch[8192];   // phase-local               32768B
    __shared__ float cxL[64];         // block-private cell state

    int* flags  = bar;
    int* genv   = bar + 4096;
    int* qdone  = bar + 4608;
    int* dedone = bar + 8704;
    int* fdone  = bar + 12800;

    const int tid = threadIdx.x, bid = blockIdx.x;
    const int lane = tid & 63;
    const int d0 = bid * 2;           // A dims
    const int bp = tid & 15;          // A: b-pair
    const int ab = bid >> 3;          // DE/C/F: batch
    const int n0 = (bid & 7) * 48;    // DE: n-slice
    const int cg = bid & 7;           // C/F: col-group (64 cols)
    const int cgA = bid >> 5;         // col-group containing A dims {2bid,2bid+1}
    const int w  = tid >> 6;          // wave id

    // ---- one-time staging ----
    for (int k = tid; k < 1280; k += NTHR) {
        const float* src = (k < 768) ? (W_ih + (size_t)k * 2048)
                                     : (W_hh + (size_t)(k - 768) * 2048);
#pragma unroll
        for (int g = 0; g < 4; ++g) {
            Wg[k * 8 + g * 2 + 0] = src[g * 512 + d0 + 0];
            Wg[k * 8 + g * 2 + 1] = src[g * 512 + d0 + 1];
        }
    }
    if (tid < 64) cxL[tid] = 0.f;
    float v8[8];
#pragma unroll
    for (int i = 0; i < 8; ++i) v8[i] = vv[lane * 8 + i];
    float4 wva[6], wvb[6];            // t-invariant Wv fragment
#pragma unroll
    for (int r = 0; r < 6; ++r) {
        const float* wv = Wv + ((size_t)(ab * Nn + n0 + w * 6 + r)) * 512 + lane * 8;
        wva[r] = *(const float4*)wv;
        wvb[r] = *(const float4*)(wv + 4);
    }
    float encR[48];                   // t-invariant enc column slice
#pragma unroll
    for (int i = 0; i < 48; ++i)
        encR[i] = enc[((size_t)(ab * Nn + n0 + i)) * 512 + tid];
    const float SHIFT = shiftbuf[0];
    const float bcF = b_c[cg * 64 + (tid & 63)];
    float bsum0 = 0.f, bsum1 = 0.f, bsum2 = 0.f, bsum3 = 0.f;
    if (tid < 64) {
        int dd = tid >> 5;
        int d = d0 + dd;
        bsum0 = b_ih[0 * 512 + d] + b_hh[0 * 512 + d];
        bsum1 = b_ih[1 * 512 + d] + b_hh[1 * 512 + d];
        bsum2 = b_ih[2 * 512 + d] + b_hh[2 * 512 + d];
        bsum3 = b_ih[3 * 512 + d] + b_hh[3 * 512 + d];
    }
    __syncthreads();

    for (int t = 0; t < Ss; ++t) {
        const int rd = t & 1, wr = 1 - rd;
        const float* hxT_rd = hxT + rd * 16384;
        float*       hxT_wr = hxT + wr * 16384;
        float*       hxB_t  = hxB + (t & 1) * 16384;   // this step's row-major hx

        // ---------- Phase A: prework -> fdone poll -> o-rows -> LSTM ----------
        {
            const float* embx_t = obuf + (size_t)(t + 1) * BD;  // [k][b], k<256
            const float* xo2 = xo - 256 * 32;
            const float* hx2 = hxT_rd - 768 * 32;
            int ks = tid >> 4;           // 32 k-chunks of 40
            int k0 = ks * 40;
            float ax[8], ay[8];
#pragma unroll
            for (int i = 0; i < 8; ++i) { ax[i] = 0.f; ay[i] = 0.f; }
            if (t) {
                // prework: emb rows (slot t+1 front, static until F(t) post-gbar)
                //        + hx(t-1) rows (crossed gbar(t-1))
#pragma unroll
                for (int kb = 0; kb < 5; ++kb) {
                    int kbase = k0 + kb * 8;
                    if (kbase >= 256 && kbase < 768) continue;   // o rows later
                    const float* base = (kbase < 256) ? embx_t : hx2;
                    float2 xv[8];
#pragma unroll
                    for (int j = 0; j < 8; ++j)
                        xv[j] = ld2_dev(base + (kbase + j) * 32 + 2 * bp);
#pragma unroll
                    for (int j = 0; j < 8; ++j) {
                        int k = kbase + j;
                        float4 wA = *(const float4*)&Wg[k * 8];
                        float4 wB = *(const float4*)&Wg[k * 8 + 4];
                        ax[0] += xv[j].x * wA.x; ay[0] += xv[j].y * wA.x;
                        ax[1] += xv[j].x * wA.y; ay[1] += xv[j].y * wA.y;
                        ax[2] += xv[j].x * wA.z; ay[2] += xv[j].y * wA.z;
                        ax[3] += xv[j].x * wA.w; ay[3] += xv[j].y * wA.w;
                        ax[4] += xv[j].x * wB.x; ay[4] += xv[j].y * wB.x;
                        ax[5] += xv[j].x * wB.y; ay[5] += xv[j].y * wB.y;
                        ax[6] += xv[j].x * wB.z; ay[6] += xv[j].y * wB.z;
                        ax[7] += xv[j].x * wB.w; ay[7] += xv[j].y * wB.w;
                    }
                }
                // poll F(t-1): 32 producers of this block's o-dims (cg == cgA)
                // + 8 readers of this block's ctxB slice (batch bid>>3).
                if (tid < 40) {
                    int fl = (tid < 32) ? (tid * 8 + cgA)
                                        : ((bid >> 3) * 8 + (tid - 32));
                    int* g = &fdone[fl * 16];
                    while (__hip_atomic_load(g, __ATOMIC_RELAXED,
                                             __HIP_MEMORY_SCOPE_AGENT) < t)
                        __builtin_amdgcn_s_sleep(1);
                }
                __syncthreads();
                // ctx-zero: safe now (F(t-1) readers of this slice finished)
                if (tid < 64)
                    st_dev(&ctxB[bid * 64 + tid], 0.f);
                // post-poll: o_prev rows
#pragma unroll
                for (int kb = 0; kb < 5; ++kb) {
                    int kbase = k0 + kb * 8;
                    if (kbase < 256 || kbase >= 768) continue;
                    float2 xv[8];
#pragma unroll
                    for (int j = 0; j < 8; ++j)
                        xv[j] = ld2_dev(xo2 + (kbase + j) * 32 + 2 * bp);
#pragma unroll
                    for (int j = 0; j < 8; ++j) {
                        int k = kbase + j;
                        float4 wA = *(const float4*)&Wg[k * 8];
                        float4 wB = *(const float4*)&Wg[k * 8 + 4];
                        ax[0] += xv[j].x * wA.x; ay[0] += xv[j].y * wA.x;
                        ax[1] += xv[j].x * wA.y; ay[1] += xv[j].y * wA.y;
                        ax[2] += xv[j].x * wA.z; ay[2] += xv[j].y * wA.z;
                        ax[3] += xv[j].x * wA.w; ay[3] += xv[j].y * wA.w;
                        ax[4] += xv[j].x * wB.x; ay[4] += xv[j].y * wB.x;
                        ax[5] += xv[j].x * wB.y; ay[5] += xv[j].y * wB.y;
                        ax[6] += xv[j].x * wB.z; ay[6] += xv[j].y * wB.z;
                        ax[7] += xv[j].x * wB.w; ay[7] += xv[j].y * wB.w;
                    }
                }
            } else {
                if (tid < 64)
                    st_dev(&ctxB[bid * 64 + tid], 0.f);
            }
#pragma unroll
            for (int c = 0; c < 8; ++c) {
                scratch[(ks * 8 + c) * 32 + 2 * bp]     = ax[c];
                scratch[(ks * 8 + c) * 32 + 2 * bp + 1] = ay[c];
            }
            __syncthreads();
            if (tid < 256) {
                int col = tid >> 5, b2 = tid & 31;
                float s = 0.f;
#pragma unroll
                for (int k2 = 0; k2 < 32; ++k2) s += scratch[(k2 * 8 + col) * 32 + b2];
                scratch[col * 32 + b2] = s;
            }
            __syncthreads();
            if (tid < 64) {
                int dd = tid >> 5, b2 = tid & 31;
                float gi = scratch[(0 * 2 + dd) * 32 + b2] + bsum0;
                float gf = scratch[(1 * 2 + dd) * 32 + b2] + bsum1;
                float gg = scratch[(2 * 2 + dd) * 32 + b2] + bsum2;
                float go = scratch[(3 * 2 + dd) * 32 + b2] + bsum3;
                float c = sigm_(gf) * cxL[tid] + sigm_(gi) * tanh_(gg);
                cxL[tid] = c;
                float h = sigm_(go) * tanh_(c);
                st_dev(&hxT_wr[(d0 + dd) * 32 + b2], h);
                st_dev(&hxB_t[b2 * 512 + d0 + dd], h);   // row-major copy for C/F
            }
        }
        gbar(flags, genv, t);

        // ---------- Phase C: q[ab][cg*64..+64) = hx[ab] @ W_h slice ----------
        {
            float* hxL  = scratch;          // 512
            float* gred = scratch + 512;    // 8*72
            hxL[tid] = ld1_dev(&hxB_t[ab * 512 + tid]);
            __syncthreads();
            int col = tid & 63, kseg = tid >> 6;   // kseg == wave id
            const float* wp = W_h + (size_t)(kseg * 64) * 512 + cg * 64 + col;
            const float* xr = hxL + kseg * 64;
            float a = 0.f;
#pragma unroll 8
            for (int kk = 0; kk < 64; ++kk)
                a += wp[(size_t)kk * 512] * xr[kk];
            gred[kseg * 72 + col] = a;
            __syncthreads();
            if (tid < 64) {
                float s = 0.f;
#pragma unroll
                for (int k2 = 0; k2 < 8; ++k2) s += gred[k2 * 72 + tid];
                st_dev(&q[ab * 512 + cg * 64 + tid], s);
            }
            __syncthreads();   // drain q stores
            if (tid == 0)
                __hip_atomic_store(&qdone[bid * 16], t + 1, __ATOMIC_RELAXED,
                                   __HIP_MEMORY_SCOPE_AGENT);
        }

        // ---------- Phase DE: poll q flags, scores + exp + ctx atomics ----------
        {
            poll8(qdone, ab, t + 1);
            float* esc = scratch;            // 48 e-values
            float q8[8];
#pragma unroll
            for (int j = 0; j < 4; ++j) {
                float2 qv = ld2_dev(&q[ab * 512 + lane * 8 + 2 * j]);
                q8[2 * j] = qv.x; q8[2 * j + 1] = qv.y;
            }
#pragma unroll
            for (int r = 0; r < 6; ++r) {
                float s = v8[0] * tanh_(q8[0] + wva[r].x) + v8[1] * tanh_(q8[1] + wva[r].y)
                        + v8[2] * tanh_(q8[2] + wva[r].z) + v8[3] * tanh_(q8[3] + wva[r].w)
                        + v8[4] * tanh_(q8[4] + wvb[r].x) + v8[5] * tanh_(q8[5] + wvb[r].y)
                        + v8[6] * tanh_(q8[6] + wvb[r].z) + v8[7] * tanh_(q8[7] + wvb[r].w);
#pragma unroll
                for (int off = 32; off > 0; off >>= 1)
                    s += __shfl_down(s, off, 64);
                if (lane == 0) esc[w * 6 + r] = __expf(s - SHIFT);
            }
            __syncthreads();
            if (tid < 48)
                alpha_e[((size_t)ab * Ss + t) * Nn + n0 + tid] = esc[tid];
            if (tid == 0) {
                float sd = 0.f;
                for (int i = 0; i < 48; ++i) sd += esc[i];
                atomicAdd(&den[t * 32 + ab], sd);
            }
            float acc = 0.f;
#pragma unroll 8
            for (int i = 0; i < 48; ++i)
                acc += esc[i] * encR[i];
            atomicAdd(&ctxB[ab * 512 + tid], acc);
            __syncthreads();   // drain atomics
            if (tid == 0)
                __hip_atomic_store(&dedone[bid * 16], t + 1, __ATOMIC_RELAXED,
                                   __HIP_MEMORY_SCOPE_AGENT);
        }

        // ---------- Phase F: o[ab][cg*64..+64) = tanh([hx|ctx/den] @ W_c + b_c) ----------
        {
            poll8(dedone, ab, t + 1);
            float* xF   = scratch;          // 1024
            float* gred = scratch + 1024;   // 8*72
            float rdn = 1.0f / ld1_dev(&den[t * 32 + ab]);
            xF[tid]       = ld1_dev(&hxB_t[ab * 512 + tid]);
            xF[512 + tid] = ld1_dev(&ctxB[ab * 512 + tid]) * rdn;
            __syncthreads();
            int col = tid & 63, kseg = tid >> 6;
            const float* wp = W_c + (size_t)(kseg * 128) * 512 + cg * 64 + col;
            const float* xr = xF + kseg * 128;
            float a = 0.f;
#pragma unroll 8
            for (int kk = 0; kk < 128; ++kk)
                a += wp[(size_t)kk * 512] * xr[kk];
            gred[kseg * 72 + col] = a;
            __syncthreads();
            if (tid < 64) {
                float s = bcF;
#pragma unroll
                for (int k2 = 0; k2 < 8; ++k2) s += gred[k2 * 72 + tid];
                float o = tanh_(s);
                st_dev(&xo[(cg * 64 + tid) * 32 + ab], o);
                obuf[(size_t)(t + 1) * BD + ab * 512 + cg * 64 + tid] = o;
            }
            __syncthreads();   // drain xo stores before posting
            if (tid == 0)
                __hip_atomic_store(&fdone[bid * 16], t + 1, __ATOMIC_RELAXED,
                                   __HIP_MEMORY_SCOPE_AGENT);
        }
        // (no second gbar: A(t+1) polls fdone for exactly what it needs)
    }
}

// Deferred logits GEMM.
__global__ void k_logits(const float* __restrict__ obuf, const float* __restrict__ W_out,
                         const float* __restrict__ b_out, float* __restrict__ out_logits) {
    int b = blockIdx.x / 24, tt = blockIdx.x % 24;
    int t0 = tt * 8;
    int tmax = min(8, Ss - t0);
    __shared__ float oL[8 * 512];
    int tid = threadIdx.x;
    for (int i = 0; i < 16; ++i) {
        int e = tid + i * 256;
        int ti = e >> 9, d = e & 511;
        oL[e] = (ti < tmax) ? obuf[(size_t)(t0 + ti + 1) * BD + b * Dd + d] : 0.f;
    }
    __syncthreads();
    int v0 = tid, v1 = tid + 256, v2 = tid + 512;
    bool h2 = (v2 < Vv);
    int v2c = h2 ? v2 : 0;
    float acc[3][8];
#pragma unroll
    for (int s = 0; s < 3; ++s)
#pragma unroll
        for (int ti = 0; ti < 8; ++ti) acc[s][ti] = 0.f;
    for (int d = 0; d < 512; ++d) {
        float w0 = W_out[d * Vv + v0];
        float w1 = W_out[d * Vv + v1];
        float w2 = W_out[d * Vv + v2c];
#pragma unroll
        for (int ti = 0; ti < 8; ++ti) {
            float o = oL[ti * 512 + d];
            acc[0][ti] += o * w0; acc[1][ti] += o * w1; acc[2][ti] += o * w2;
        }
    }
    for (int ti = 0; ti < tmax; ++ti) {
        size_t base = (size_t)b * (Ss * Vv) + (size_t)(t0 + ti) * Vv;
        out_logits[base + v0] = acc[0][ti] + b_out[v0];
        out_logits[base + v1] = acc[1][ti] + b_out[v1];
        if (h2) out_logits[base + v2] = acc[2][ti] + b_out[v2];
    }
}

// Normalize alphas: alpha /= denom[b,t]
__global__ void k_anorm(float* __restrict__ alph, const float* __restrict__ den) {
    int i = blockIdx.x * 256 + threadIdx.x;
    if (i < ALPHA_SZ) {
        int bt = i / Nn;
        int t = bt % Ss, b = bt / Ss;
        alph[i] = alph[i] / den[t * 32 + b];
    }
}

extern "C" void kernel_launch(void* const* d_in, const int* in_sizes, int n_in,
                              void* d_out, int out_size, void* d_ws, size_t ws_size,
                              hipStream_t stream) {
    const float* enc   = (const float*)d_in[0];
    const int*   tgt   = (const int*)d_in[1];
    const float* emb   = (const float*)d_in[2];
    const float* W_ih  = (const float*)d_in[3];
    const float* b_ih  = (const float*)d_in[4];
    const float* W_hh  = (const float*)d_in[5];
    const float* b_hh  = (const float*)d_in[6];
    const float* W_h   = (const float*)d_in[7];
    const float* W_v   = (const float*)d_in[8];
    const float* vv    = (const float*)d_in[9];
    const float* W_c   = (const float*)d_in[10];
    const float* b_c   = (const float*)d_in[11];
    const float* W_out = (const float*)d_in[12];
    const float* b_out = (const float*)d_in[13];

    float* wsf   = (float*)d_ws;
    int*   tok   = (int*)d_ws;
    float* shiftb= wsf + OFF_SHIFT;
    float* Wv    = wsf + OFF_WV;
    float* hxT   = wsf + OFF_HXT;
    float* xo    = wsf + OFF_XO;
    float* hxB   = wsf + OFF_HXB;
    float* den   = wsf + OFF_DEN;
    float* q     = wsf + OFF_Q;
    float* ctxB  = wsf + OFF_CTXB;
    float* obuf  = wsf + OFF_OBUF;
    int*   bar   = (int*)(wsf + OFF_BAR);

    float* out_logits = (float*)d_out;
    float* out_alphas = (float*)d_out + LOGITS_SZ;

    k_setup<<<96, 256, 0, stream>>>(tgt, vv, hxT, bar, tok, shiftb);
    k_embx<<<(Ss * 8192 + 255) / 256, 256, 0, stream>>>(emb, tok, obuf);
    k_wv<<<768, 256, 0, stream>>>(enc, W_v, Wv);
    k_decode<<<NBLK, NTHR, 0, stream>>>(enc, W_ih, b_ih, W_hh, b_hh, W_h, vv,
                                        W_c, b_c, Wv, shiftb,
                                        hxT, xo, hxB, den, q, ctxB, obuf,
                                        out_alphas, bar);
    k_logits<<<768, 256, 0, stream>>>(obuf, W_out, b_out, out_logits);
    k_anorm<<<(ALPHA_SZ + 255) / 256, 256, 0, stream>>>(out_alphas, den);
}

// Round 16
// 5093.740 us; speedup vs baseline: 1.0958x; 1.0958x over previous
//
#include <hip/hip_runtime.h>
#include <cstdint>

#define Bb 32
#define Cc 512
#define Nn 384
#define Vv 600
#define Ee 256
#define Dd 512
#define Tt 192
#define Ss 191
#define EOS_TOK 130
#define BD (Bb*Dd)          // 16384
#define NBLK 256
#define NTHR 512

// ---- ws layout (float offsets) ----
#define OFF_TOK   0                      // int tok[Ss*Bb]
#define OFF_SHIFT 8192                   // float shift[1]
#define OFF_WV    8256                   // Bb*Nn*Dd = 6291456
#define OFF_HXT   6299712                // 2*16384 hxT [par][d][b] (sc1)
#define OFF_XO    6332480                // 16384 xo [d][b] (sc1)
#define OFF_HXB   6348864                // 16384 hxB [b][d] (sc1)
#define OFF_DEN   6365248                // den[t][b] 191*32 (pad 8192, zeroed once)
#define OFF_Q     6373440                // q[b][d] 32*512 (sc1)
#define OFF_CTXB  6389824                // ctxB[b][c] 32*512 (atomics + sc1)
#define OFF_OBUF  6406208                // 192*BD; slot t+1 front doubles as embx[t]
#define OFF_BAR   9551936                // flags+genv+qdone+dedone

#define LOGITS_SZ (Bb*Ss*Vv)  // 3667200
#define ALPHA_SZ  (Bb*Ss*Nn)  // 2347008

__device__ __forceinline__ float sigm_(float x) {
    float e = __expf(-x);
    return __builtin_amdgcn_rcpf(1.0f + e);
}
__device__ __forceinline__ float tanh_(float x) {
    float xc = fminf(15.0f, fmaxf(-15.0f, x));
    float e = __expf(2.0f * xc);
    return (e - 1.0f) * __builtin_amdgcn_rcpf(e + 1.0f);
}

// Write-through device store (sc1): at LLC once vmcnt retires; __syncthreads
// drains vmcnt, so no release fence is ever needed.
__device__ __forceinline__ void st_dev(float* p, float v) {
    __hip_atomic_store(p, v, __ATOMIC_RELAXED, __HIP_MEMORY_SCOPE_AGENT);
}
__device__ __forceinline__ float ld1_dev(const float* p) {
    return __hip_atomic_load(p, __ATOMIC_RELAXED, __HIP_MEMORY_SCOPE_AGENT);
}
// 8-byte coherent load (sc1 bypass, relaxed).
__device__ __forceinline__ float2 ld2_dev(const float* p) {
    unsigned long long u = __hip_atomic_load((const unsigned long long*)p,
                                             __ATOMIC_RELAXED,
                                             __HIP_MEMORY_SCOPE_AGENT);
    float2 f;
    f.x = __uint_as_float((unsigned int)u);
    f.y = __uint_as_float((unsigned int)(u >> 32));
    return f;
}

// Flag-array device barrier (proven aggregator protocol).
__device__ __forceinline__ void gbar(int* flags, int* genv, int ibar) {
    __syncthreads();   // drains vmcnt: all sc1 data stores ack'd at LLC
    const int target = ibar + 1;
    if (threadIdx.x == 0)
        __hip_atomic_store(&flags[blockIdx.x * 16], target, __ATOMIC_RELAXED,
                           __HIP_MEMORY_SCOPE_AGENT);
    if (blockIdx.x == 0) {
        if (threadIdx.x < 64) {
            int l = threadIdx.x * 4;
            for (;;) {
                int f0 = __hip_atomic_load(&flags[(l + 0) * 16], __ATOMIC_RELAXED,
                                           __HIP_MEMORY_SCOPE_AGENT);
                int f1 = __hip_atomic_load(&flags[(l + 1) * 16], __ATOMIC_RELAXED,
                                           __HIP_MEMORY_SCOPE_AGENT);
                int f2 = __hip_atomic_load(&flags[(l + 2) * 16], __ATOMIC_RELAXED,
                                           __HIP_MEMORY_SCOPE_AGENT);
                int f3 = __hip_atomic_load(&flags[(l + 3) * 16], __ATOMIC_RELAXED,
                                           __HIP_MEMORY_SCOPE_AGENT);
                if (__all(f0 >= target && f1 >= target &&
                          f2 >= target && f3 >= target)) break;
                __builtin_amdgcn_s_sleep(1);
            }
            if (threadIdx.x < 32)
                __hip_atomic_store(&genv[threadIdx.x * 16], target,
                                   __ATOMIC_RELAXED, __HIP_MEMORY_SCOPE_AGENT);
        }
    } else if (threadIdx.x == 0) {
        int* g = &genv[(blockIdx.x >> 3) * 16];
        while (__hip_atomic_load(g, __ATOMIC_RELAXED,
                                 __HIP_MEMORY_SCOPE_AGENT) < target)
            __builtin_amdgcn_s_sleep(2);
    }
    __syncthreads();
}

// Block-wide 8-flag group poll (q/ctx handoff).
__device__ __forceinline__ void poll8(int* base, int grp, int target) {
    if (threadIdx.x < 64) {
        int* g = &base[(grp * 8 + (threadIdx.x & 7)) * 16];
        while (__hip_atomic_load(g, __ATOMIC_RELAXED,
                                 __HIP_MEMORY_SCOPE_AGENT) < target)
            __builtin_amdgcn_s_sleep(1);
    }
    __syncthreads();
}

// S0: zero state/flags/denoms, token sequence, exp-shift = sum|v|.
__global__ void k_setup(const int* __restrict__ tgt, const float* __restrict__ vv,
                        float* zbase, int* bar, int* tok, float* shiftbuf) {
    int gid = blockIdx.x * 256 + threadIdx.x;
    for (int i = gid; i < 73728; i += 96 * 256) zbase[i] = 0.f;   // hxT,xo,hxB,den
    if (gid < 12800) bar[gid] = 0;  // flags+genv+qdone+dedone
    if (blockIdx.x == 0) {
        __shared__ int is64;
        if (threadIdx.x == 0) {
            int a = 1;
            for (int k = 0; k < 32; ++k) if (tgt[2 * k + 1] != 0) a = 0;
            is64 = a;
        }
        __syncthreads();
        int b = threadIdx.x;
        if (b < Bb) {
            int fin = 0;
            tok[0 * Bb + b] = 0;
            for (int s = 1; s < Ss; ++s) {
                int li = b * Tt + s;
                int nt = is64 ? tgt[2 * li] : tgt[li];
                if (nt == EOS_TOK) fin = 1;
                tok[s * Bb + b] = fin ? 0 : nt;
            }
        }
    }
    if (blockIdx.x == 1) {
        __shared__ float sred[256];
        int tid = threadIdx.x;
        sred[tid] = fabsf(vv[tid]) + fabsf(vv[tid + 256]);
        __syncthreads();
        for (int s = 128; s > 0; s >>= 1) {
            if (tid < s) sred[tid] += sred[tid + s];
            __syncthreads();
        }
        if (tid == 0) shiftbuf[0] = sred[0];
    }
}

// S1: gather embeddings for all steps into obuf slot fronts: [t][k][b]
__global__ void k_embx(const float* __restrict__ emb, const int* __restrict__ tok,
                       float* __restrict__ obuf) {
    int i = blockIdx.x * 256 + threadIdx.x;
    if (i < Ss * 8192) {
        int t = i >> 13, e = i & 8191;
        int k = e >> 5, b = e & 31;
        obuf[(size_t)(t + 1) * BD + e] = emb[(size_t)tok[t * 32 + b] * Ee + k];
    }
}

// S2: Wv[b,n,d] = sum_c enc[b,n,c] * W_v[c,d]
__global__ void k_wv(const float* __restrict__ enc, const float* __restrict__ Wv_w,
                     float* __restrict__ Wv) {
    int b = blockIdx.x / 24, nt = blockIdx.x % 24, n0 = nt * 16;
    __shared__ float encL[16 * 512];
    for (int i = 0; i < 32; ++i) {
        int e = threadIdx.x + i * 256;
        int ni = e >> 9, c = e & 511;
        encL[e] = enc[((b * Nn) + (n0 + ni)) * Cc + c];
    }
    __syncthreads();
    int d0 = threadIdx.x, d1 = threadIdx.x + 256;
    float a0[16], a1[16];
#pragma unroll
    for (int i = 0; i < 16; ++i) { a0[i] = 0.f; a1[i] = 0.f; }
    for (int c = 0; c < 512; ++c) {
        float w0 = Wv_w[c * Dd + d0], w1 = Wv_w[c * Dd + d1];
#pragma unroll
        for (int i = 0; i < 16; ++i) {
            float ev = encL[i * 512 + c];
            a0[i] += ev * w0; a1[i] += ev * w1;
        }
    }
#pragma unroll
    for (int i = 0; i < 16; ++i) {
        Wv[((b * Nn) + (n0 + i)) * Dd + d0] = a0[i];
        Wv[((b * Nn) + (n0 + i)) * Dd + d1] = a1[i];
    }
}

// Persistent decode: 256 blocks x 512 threads.
// Per step: A (dim-distributed, LDS weights) -> gbar1 -> C (batch x col-slice,
// L2-resident W_h slice) -> qdone flags -> DE -> dedone flags -> F (batch x
// col-slice, L2-resident W_c slice) -> gbar2.  2 global barriers + 2 light
// flag handoffs. (Measured optimum; 5 sync-topology alternatives and 4
// phase-A variants all tested slower — see session journal r10-r15.)
__global__ __launch_bounds__(NTHR) void k_decode(
    const float* __restrict__ enc, const float* __restrict__ W_ih,
    const float* __restrict__ b_ih, const float* __restrict__ W_hh,
    const float* __restrict__ b_hh, const float* __restrict__ W_h,
    const float* __restrict__ vv, const float* __restrict__ W_c,
    const float* __restrict__ b_c, const float* __restrict__ Wv,
    const float* __restrict__ shiftbuf,
    float* __restrict__ hxT, float* __restrict__ xo, float* __restrict__ hxB,
    float* __restrict__ den, float* __restrict__ q, float* __restrict__ ctxB,
    float* __restrict__ obuf, float* __restrict__ alpha_e, int* bar)
{
    __shared__ float Wg[1280 * 8];    // A: gate cols [k][g*2+dd]  40960B
    __shared__ float scratch[8192];   // phase-local               32768B
    __shared__ float cxL[64];         // block-private cell state

    int* flags  = bar;
    int* genv   = bar + 4096;
    int* qdone  = bar + 4608;
    int* dedone = bar + 8704;

    const int tid = threadIdx.x, bid = blockIdx.x;
    const int lane = tid & 63;
    const int d0 = bid * 2;           // A dims
    const int bp = tid & 15;          // A: b-pair
    const int ab = bid >> 3;          // DE/C/F: batch
    const int n0 = (bid & 7) * 48;    // DE: n-slice
    const int cg = bid & 7;           // C/F: col-group (64 cols)
    const int w  = tid >> 6;          // wave id

    // ---- one-time staging ----
    for (int k = tid; k < 1280; k += NTHR) {
        const float* src = (k < 768) ? (W_ih + (size_t)k * 2048)
                                     : (W_hh + (size_t)(k - 768) * 2048);
#pragma unroll
        for (int g = 0; g < 4; ++g) {
            Wg[k * 8 + g * 2 + 0] = src[g * 512 + d0 + 0];
            Wg[k * 8 + g * 2 + 1] = src[g * 512 + d0 + 1];
        }
    }
    if (tid < 64) cxL[tid] = 0.f;
    float v8[8];
#pragma unroll
    for (int i = 0; i < 8; ++i) v8[i] = vv[lane * 8 + i];
    float4 wva[6], wvb[6];            // t-invariant Wv fragment
#pragma unroll
    for (int r = 0; r < 6; ++r) {
        const float* wv = Wv + ((size_t)(ab * Nn + n0 + w * 6 + r)) * 512 + lane * 8;
        wva[r] = *(const float4*)wv;
        wvb[r] = *(const float4*)(wv + 4);
    }
    float encR[48];                   // t-invariant enc column slice
#pragma unroll
    for (int i = 0; i < 48; ++i)
        encR[i] = enc[((size_t)(ab * Nn + n0 + i)) * 512 + tid];
    const float SHIFT = shiftbuf[0];
    const float bcF = b_c[cg * 64 + (tid & 63)];
    float bsum0 = 0.f, bsum1 = 0.f, bsum2 = 0.f, bsum3 = 0.f;
    if (tid < 64) {
        int dd = tid >> 5;
        int d = d0 + dd;
        bsum0 = b_ih[0 * 512 + d] + b_hh[0 * 512 + d];
        bsum1 = b_ih[1 * 512 + d] + b_hh[1 * 512 + d];
        bsum2 = b_ih[2 * 512 + d] + b_hh[2 * 512 + d];
        bsum3 = b_ih[3 * 512 + d] + b_hh[3 * 512 + d];
    }
    __syncthreads();

    int ib = 0;
    for (int t = 0; t < Ss; ++t) {
        const int rd = t & 1, wr = 1 - rd;
        const float* hxT_rd = hxT + rd * 16384;
        float*       hxT_wr = hxT + wr * 16384;

        // ---------- Phase A: gates (full K) + LSTM + ctx-zero ----------
        {
            // zero this block's ctxB slice for THIS step's DE atomics
            // (safe: A(t) runs after gbar2(t-1), which follows F(t-1)'s reads)
            if (tid < 64)
                st_dev(&ctxB[bid * 64 + tid], 0.f);
            const float* embx_t = obuf + (size_t)(t + 1) * BD;  // [k][b], k<256
            const float* xo2 = xo - 256 * 32;
            const float* hx2 = hxT_rd - 768 * 32;
            int ks = tid >> 4;           // 32 k-chunks of 40
            int k0 = ks * 40;
            float ax[8], ay[8];
#pragma unroll
            for (int i = 0; i < 8; ++i) { ax[i] = 0.f; ay[i] = 0.f; }
            if (t) {
#pragma unroll
                for (int kb = 0; kb < 5; ++kb) {
                    int kbase = k0 + kb * 8;
                    float2 xv[8];
#pragma unroll
                    for (int j = 0; j < 8; ++j) {      // 8 outstanding sc1 loads
                        int k = kbase + j;
                        const float* base = (k < 256) ? embx_t : ((k < 768) ? xo2 : hx2);
                        xv[j] = ld2_dev(base + k * 32 + 2 * bp);
                    }
#pragma unroll
                    for (int j = 0; j < 8; ++j) {
                        int k = kbase + j;
                        float4 wA = *(const float4*)&Wg[k * 8];
                        float4 wB = *(const float4*)&Wg[k * 8 + 4];
                        ax[0] += xv[j].x * wA.x; ay[0] += xv[j].y * wA.x;
                        ax[1] += xv[j].x * wA.y; ay[1] += xv[j].y * wA.y;
                        ax[2] += xv[j].x * wA.z; ay[2] += xv[j].y * wA.z;
                        ax[3] += xv[j].x * wA.w; ay[3] += xv[j].y * wA.w;
                        ax[4] += xv[j].x * wB.x; ay[4] += xv[j].y * wB.x;
                        ax[5] += xv[j].x * wB.y; ay[5] += xv[j].y * wB.y;
                        ax[6] += xv[j].x * wB.z; ay[6] += xv[j].y * wB.z;
                        ax[7] += xv[j].x * wB.w; ay[7] += xv[j].y * wB.w;
                    }
                }
            }
#pragma unroll
            for (int c = 0; c < 8; ++c) {
                scratch[(ks * 8 + c) * 32 + 2 * bp]     = ax[c];
                scratch[(ks * 8 + c) * 32 + 2 * bp + 1] = ay[c];
            }
            __syncthreads();
            if (tid < 256) {
                int col = tid >> 5, b2 = tid & 31;
                float s = 0.f;
#pragma unroll
                for (int k2 = 0; k2 < 32; ++k2) s += scratch[(k2 * 8 + col) * 32 + b2];
                scratch[col * 32 + b2] = s;
            }
            __syncthreads();
            if (tid < 64) {
                int dd = tid >> 5, b2 = tid & 31;
                float gi = scratch[(0 * 2 + dd) * 32 + b2] + bsum0;
                float gf = scratch[(1 * 2 + dd) * 32 + b2] + bsum1;
                float gg = scratch[(2 * 2 + dd) * 32 + b2] + bsum2;
                float go = scratch[(3 * 2 + dd) * 32 + b2] + bsum3;
                float c = sigm_(gf) * cxL[tid] + sigm_(gi) * tanh_(gg);
                cxL[tid] = c;
                float h = sigm_(go) * tanh_(c);
                st_dev(&hxT_wr[(d0 + dd) * 32 + b2], h);
                st_dev(&hxB[b2 * 512 + d0 + dd], h);   // row-major copy for C/F
            }
        }
        gbar(flags, genv, ib++);

        // ---------- Phase C: q[ab][cg*64..+64) = hx[ab] @ W_h slice ----------
        {
            float* hxL  = scratch;          // 512
            float* gred = scratch + 512;    // 8*72
            hxL[tid] = ld1_dev(&hxB[ab * 512 + tid]);
            __syncthreads();
            int col = tid & 63, kseg = tid >> 6;   // kseg == wave id
            const float* wp = W_h + (size_t)(kseg * 64) * 512 + cg * 64 + col;
            const float* xr = hxL + kseg * 64;
            float a = 0.f;
#pragma unroll 8
            for (int kk = 0; kk < 64; ++kk)
                a += wp[(size_t)kk * 512] * xr[kk];
            gred[kseg * 72 + col] = a;
            __syncthreads();
            if (tid < 64) {
                float s = 0.f;
#pragma unroll
                for (int k2 = 0; k2 < 8; ++k2) s += gred[k2 * 72 + tid];
                st_dev(&q[ab * 512 + cg * 64 + tid], s);
            }
            __syncthreads();   // drain q stores
            if (tid == 0)
                __hip_atomic_store(&qdone[bid * 16], t + 1, __ATOMIC_RELAXED,
                                   __HIP_MEMORY_SCOPE_AGENT);
        }

        // ---------- Phase DE: poll q flags, scores + exp + ctx atomics ----------
        {
            poll8(qdone, ab, t + 1);
            float* esc = scratch;            // 48 e-values
            float q8[8];
#pragma unroll
            for (int j = 0; j < 4; ++j) {
                float2 qv = ld2_dev(&q[ab * 512 + lane * 8 + 2 * j]);
                q8[2 * j] = qv.x; q8[2 * j + 1] = qv.y;
            }
#pragma unroll
            for (int r = 0; r < 6; ++r) {
                float s = v8[0] * tanh_(q8[0] + wva[r].x) + v8[1] * tanh_(q8[1] + wva[r].y)
                        + v8[2] * tanh_(q8[2] + wva[r].z) + v8[3] * tanh_(q8[3] + wva[r].w)
                        + v8[4] * tanh_(q8[4] + wvb[r].x) + v8[5] * tanh_(q8[5] + wvb[r].y)
                        + v8[6] * tanh_(q8[6] + wvb[r].z) + v8[7] * tanh_(q8[7] + wvb[r].w);
#pragma unroll
                for (int off = 32; off > 0; off >>= 1)
                    s += __shfl_down(s, off, 64);
                if (lane == 0) esc[w * 6 + r] = __expf(s - SHIFT);
            }
            __syncthreads();
            if (tid < 48)
                alpha_e[((size_t)ab * Ss + t) * Nn + n0 + tid] = esc[tid];
            if (tid == 0) {
                float sd = 0.f;
                for (int i = 0; i < 48; ++i) sd += esc[i];
                atomicAdd(&den[t * 32 + ab], sd);
            }
            float acc = 0.f;
#pragma unroll 8
            for (int i = 0; i < 48; ++i)
                acc += esc[i] * encR[i];
            atomicAdd(&ctxB[ab * 512 + tid], acc);
            __syncthreads();   // drain atomics
            if (tid == 0)
                __hip_atomic_store(&dedone[bid * 16], t + 1, __ATOMIC_RELAXED,
                                   __HIP_MEMORY_SCOPE_AGENT);
        }

        // ---------- Phase F: o[ab][cg*64..+64) = tanh([hx|ctx/den] @ W_c + b_c) ----------
        {
            poll8(dedone, ab, t + 1);
            float* xF   = scratch;          // 1024
            float* gred = scratch + 1024;   // 8*72
            float rdn = 1.0f / ld1_dev(&den[t * 32 + ab]);
            xF[tid]       = ld1_dev(&hxB[ab * 512 + tid]);
            xF[512 + tid] = ld1_dev(&ctxB[ab * 512 + tid]) * rdn;
            __syncthreads();
            int col = tid & 63, kseg = tid >> 6;
            const float* wp = W_c + (size_t)(kseg * 128) * 512 + cg * 64 + col;
            const float* xr = xF + kseg * 128;
            float a = 0.f;
#pragma unroll 8
            for (int kk = 0; kk < 128; ++kk)
                a += wp[(size_t)kk * 512] * xr[kk];
            gred[kseg * 72 + col] = a;
            __syncthreads();
            if (tid < 64) {
                float s = bcF;
#pragma unroll
                for (int k2 = 0; k2 < 8; ++k2) s += gred[k2 * 72 + tid];
                float o = tanh_(s);
                st_dev(&xo[(cg * 64 + tid) * 32 + ab], o);
                obuf[(size_t)(t + 1) * BD + ab * 512 + cg * 64 + tid] = o;
            }
        }
        gbar(flags, genv, ib++);
    }
}

// Deferred logits GEMM.
__global__ void k_logits(const float* __restrict__ obuf, const float* __restrict__ W_out,
                         const float* __restrict__ b_out, float* __restrict__ out_logits) {
    int b = blockIdx.x / 24, tt = blockIdx.x % 24;
    int t0 = tt * 8;
    int tmax = min(8, Ss - t0);
    __shared__ float oL[8 * 512];
    int tid = threadIdx.x;
    for (int i = 0; i < 16; ++i) {
        int e = tid + i * 256;
        int ti = e >> 9, d = e & 511;
        oL[e] = (ti < tmax) ? obuf[(size_t)(t0 + ti + 1) * BD + b * Dd + d] : 0.f;
    }
    __syncthreads();
    int v0 = tid, v1 = tid + 256, v2 = tid + 512;
    bool h2 = (v2 < Vv);
    int v2c = h2 ? v2 : 0;
    float acc[3][8];
#pragma unroll
    for (int s = 0; s < 3; ++s)
#pragma unroll
        for (int ti = 0; ti < 8; ++ti) acc[s][ti] = 0.f;
    for (int d = 0; d < 512; ++d) {
        float w0 = W_out[d * Vv + v0];
        float w1 = W_out[d * Vv + v1];
        float w2 = W_out[d * Vv + v2c];
#pragma unroll
        for (int ti = 0; ti < 8; ++ti) {
            float o = oL[ti * 512 + d];
            acc[0][ti] += o * w0; acc[1][ti] += o * w1; acc[2][ti] += o * w2;
        }
    }
    for (int ti = 0; ti < tmax; ++ti) {
        size_t base = (size_t)b * (Ss * Vv) + (size_t)(t0 + ti) * Vv;
        out_logits[base + v0] = acc[0][ti] + b_out[v0];
        out_logits[base + v1] = acc[1][ti] + b_out[v1];
        if (h2) out_logits[base + v2] = acc[2][ti] + b_out[v2];
    }
}

// Normalize alphas: alpha /= denom[b,t]
__global__ void k_anorm(float* __restrict__ alph, const float* __restrict__ den) {
    int i = blockIdx.x * 256 + threadIdx.x;
    if (i < ALPHA_SZ) {
        int bt = i / Nn;
        int t = bt % Ss, b = bt / Ss;
        alph[i] = alph[i] / den[t * 32 + b];
    }
}

extern "C" void kernel_launch(void* const* d_in, const int* in_sizes, int n_in,
                              void* d_out, int out_size, void* d_ws, size_t ws_size,
                              hipStream_t stream) {
    const float* enc   = (const float*)d_in[0];
    const int*   tgt   = (const int*)d_in[1];
    const float* emb   = (const float*)d_in[2];
    const float* W_ih  = (const float*)d_in[3];
    const float* b_ih  = (const float*)d_in[4];
    const float* W_hh  = (const float*)d_in[5];
    const float* b_hh  = (const float*)d_in[6];
    const float* W_h   = (const float*)d_in[7];
    const float* W_v   = (const float*)d_in[8];
    const float* vv    = (const float*)d_in[9];
    const float* W_c   = (const float*)d_in[10];
    const float* b_c   = (const float*)d_in[11];
    const float* W_out = (const float*)d_in[12];
    const float* b_out = (const float*)d_in[13];

    float* wsf   = (float*)d_ws;
    int*   tok   = (int*)d_ws;
    float* shiftb= wsf + OFF_SHIFT;
    float* Wv    = wsf + OFF_WV;
    float* hxT   = wsf + OFF_HXT;
    float* xo    = wsf + OFF_XO;
    float* hxB   = wsf + OFF_HXB;
    float* den   = wsf + OFF_DEN;
    float* q     = wsf + OFF_Q;
    float* ctxB  = wsf + OFF_CTXB;
    float* obuf  = wsf + OFF_OBUF;
    int*   bar   = (int*)(wsf + OFF_BAR);

    float* out_logits = (float*)d_out;
    float* out_alphas = (float*)d_out + LOGITS_SZ;

    k_setup<<<96, 256, 0, stream>>>(tgt, vv, hxT, bar, tok, shiftb);
    k_embx<<<(Ss * 8192 + 255) / 256, 256, 0, stream>>>(emb, tok, obuf);
    k_wv<<<768, 256, 0, stream>>>(enc, W_v, Wv);
    k_decode<<<NBLK, NTHR, 0, stream>>>(enc, W_ih, b_ih, W_hh, b_hh, W_h, vv,
                                        W_c, b_c, Wv, shiftb,
                                        hxT, xo, hxB, den, q, ctxB, obuf,
                                        out_alphas, bar);
    k_logits<<<768, 256, 0, stream>>>(obuf, W_out, b_out, out_logits);
    k_anorm<<<(ALPHA_SZ + 255) / 256, 256, 0, stream>>>(out_alphas, den);
}